// Round 3
// baseline (6426.387 us; speedup 1.0000x reference)
//
#include <hip/hip_runtime.h>
#include <cstdint>
#include <cstddef>
#include <cstring>

#define H 8192
#define NNZ 1000000
#define B 128
#define T 64

// ---------------- CSR build ----------------
__global__ void hist_kernel(const int* __restrict__ rows, int nnz, int* __restrict__ count) {
    int j = blockIdx.x * blockDim.x + threadIdx.x;
    if (j < nnz) atomicAdd(&count[rows[j]], 1);
}

// grid=2 blocks, 1024 threads: block 0 scans array A, block 1 scans array B.
__global__ void scan_kernel(const int* __restrict__ cnt0, int* __restrict__ rp0, int* __restrict__ cur0,
                            const int* __restrict__ cnt1, int* __restrict__ rp1, int* __restrict__ cur1) {
    const int* cnt = (blockIdx.x == 0) ? cnt0 : cnt1;
    int* rp  = (blockIdx.x == 0) ? rp0 : rp1;
    int* cur = (blockIdx.x == 0) ? cur0 : cur1;
    __shared__ int buf[1024];
    __shared__ int carry;
    int tid = threadIdx.x;
    if (tid == 0) carry = 0;
    __syncthreads();
    for (int base = 0; base < H; base += 1024) {
        int v = cnt[base + tid];
        buf[tid] = v;
        __syncthreads();
        for (int off = 1; off < 1024; off <<= 1) {
            int t = (tid >= off) ? buf[tid - off] : 0;
            __syncthreads();
            buf[tid] += t;
            __syncthreads();
        }
        int incl = buf[tid];
        int excl = incl - v;
        int c = carry;
        rp[base + tid]  = c + excl;
        cur[base + tid] = c + excl;
        __syncthreads();
        if (tid == 1023) carry = c + incl;
        __syncthreads();
    }
    if (tid == 0) rp[H] = carry;
}

// packs (col, val) into int2 in CSR order
__global__ void scatter_kernel(const int* __restrict__ rows, const int* __restrict__ cols,
                               const float* __restrict__ vals, int nnz,
                               int* __restrict__ cursor, int2* __restrict__ opair) {
    int j = blockIdx.x * blockDim.x + threadIdx.x;
    if (j < nnz) {
        int r = rows[j];
        int p = atomicAdd(&cursor[r], 1);
        opair[p] = make_int2(cols[j], __float_as_int(vals[j]));
    }
}

// ---------------- transpose src[R][C] -> dst[C][R]  (R,C multiples of 32) ----------------
__global__ void transpose_kernel(const float* __restrict__ src, float* __restrict__ dst,
                                 int R, int C) {
    __shared__ float tile[32][33];
    int c0 = blockIdx.x * 32, r0 = blockIdx.y * 32;
    int x = threadIdx.x, y = threadIdx.y;
    #pragma unroll
    for (int i = y; i < 32; i += 8) {
        tile[i][x] = src[(size_t)(r0 + i) * C + (c0 + x)];
    }
    __syncthreads();
    #pragma unroll
    for (int i = y; i < 32; i += 8) {
        dst[(size_t)(c0 + i) * R + (r0 + x)] = tile[x][i];
    }
}

// ---------------- ih precompute: pre[t,h,b] = bias + spmm(ih, xT[t]) ----------------
// 256 threads = 4 waves, one row per wave. XCD-swizzled so XCD k owns t in [8k, 8k+8):
// its 4MB x-slice stays resident in that XCD's private 4MB L2 -> each slice fetched
// from HBM once instead of ~19x.
__global__ void __launch_bounds__(256) ih_pre_kernel(
    const int* __restrict__ rp, const int2* __restrict__ pair,
    const float* __restrict__ xT, float* __restrict__ pre,
    const float* __restrict__ bias_ih, const float* __restrict__ bias_hh) {
    int wave = threadIdx.x >> 6;
    int b2   = threadIdx.x & 63;          // covers batch elements 2*b2, 2*b2+1
    // blocks round-robin across 8 XCDs by blockIdx.x&7 -> give XCD k a contiguous
    // 65536-work-item chunk (= 8 consecutive t slices).
    int work = ((blockIdx.x & 7) << 16) + ((blockIdx.x >> 3) << 2) + wave;
    int t = work >> 13;                   // H = 8192 = 2^13
    int r = work & (H - 1);
    const float2* __restrict__ xt2 = (const float2*)(xT + (size_t)t * H * B);
    float bias = bias_ih[r] + bias_hh[r];
    float ax = bias, ay = bias;
    int s = rp[r], e = rp[r + 1];
    int j = s;
    for (; j + 8 <= e; j += 8) {
        int2 p[8];
        #pragma unroll
        for (int u = 0; u < 8; ++u) p[u] = pair[j + u];
        float2 g[8];
        #pragma unroll
        for (int u = 0; u < 8; ++u) g[u] = xt2[(size_t)p[u].x * 64 + b2];
        #pragma unroll
        for (int u = 0; u < 8; ++u) {
            float v = __int_as_float(p[u].y);
            ax = fmaf(v, g[u].x, ax); ay = fmaf(v, g[u].y, ay);
        }
    }
    for (; j < e; ++j) {
        int2 pj = pair[j];
        float2 g = xt2[(size_t)pj.x * 64 + b2];
        float v = __int_as_float(pj.y);
        ax = fmaf(v, g.x, ax);
        ay = fmaf(v, g.y, ay);
    }
    float2 o; o.x = ax; o.y = ay;
    double od; __builtin_memcpy(&od, &o, 8);
    __builtin_nontemporal_store(od, (double*)(pre + (size_t)work * B) + b2);
}

// ---------------- one recurrence step: 4 waves/block, one row per wave ----------------
__global__ void __launch_bounds__(256) step_kernel(
    const int* __restrict__ rp, const int2* __restrict__ pair,
    const float* __restrict__ hprev, float* __restrict__ hnew, float* __restrict__ pre_t) {
    int wave = threadIdx.x >> 6;
    int b2   = threadIdx.x & 63;
    int r = (blockIdx.x << 2) + wave;
    const float2* __restrict__ h2 = (const float2*)hprev;
    double pd = __builtin_nontemporal_load((const double*)(pre_t + (size_t)r * B) + b2);
    float2 p; __builtin_memcpy(&p, &pd, 8);
    float ax = p.x, ay = p.y;
    int s = rp[r], e = rp[r + 1];
    int j = s;
    for (; j + 8 <= e; j += 8) {
        int2 q[8];
        #pragma unroll
        for (int u = 0; u < 8; ++u) q[u] = pair[j + u];
        float2 g[8];
        #pragma unroll
        for (int u = 0; u < 8; ++u) g[u] = h2[(size_t)q[u].x * 64 + b2];
        #pragma unroll
        for (int u = 0; u < 8; ++u) {
            float v = __int_as_float(q[u].y);
            ax = fmaf(v, g[u].x, ax); ay = fmaf(v, g[u].y, ay);
        }
    }
    for (; j < e; ++j) {
        int2 qj = pair[j];
        float2 g = h2[(size_t)qj.x * 64 + b2];
        float v = __int_as_float(qj.y);
        ax = fmaf(v, g.x, ax);
        ay = fmaf(v, g.y, ay);
    }
    float hx = tanhf(ax), hy = tanhf(ay);
    float2 o; o.x = hx; o.y = hy;
    ((float2*)hnew)[(size_t)r * 64 + b2] = o;        // cached: gathered next step
    double od; __builtin_memcpy(&od, &o, 8);
    __builtin_nontemporal_store(od, (double*)(pre_t + (size_t)r * B) + b2);  // streaming outT
}

extern "C" void kernel_launch(void* const* d_in, const int* in_sizes, int n_in,
                              void* d_out, int out_size, void* d_ws, size_t ws_size,
                              hipStream_t stream) {
    const float* x        = (const float*)d_in[0];
    const int*   ih_idx   = (const int*)d_in[1];
    const float* ih_val   = (const float*)d_in[2];
    const int*   hh_idx   = (const int*)d_in[3];
    const float* hh_val   = (const float*)d_in[4];
    const float* bias_ih  = (const float*)d_in[5];
    const float* bias_hh  = (const float*)d_in[6];
    const int* ih_rows = ih_idx;
    const int* ih_cols = ih_idx + NNZ;
    const int* hh_rows = hh_idx;
    const int* hh_cols = hh_idx + NNZ;

    char* ws = (char*)d_ws;
    size_t off = 0;
    auto alloc = [&](size_t bytes) -> void* {
        void* p = ws + off;
        off += (bytes + 255) & ~(size_t)255;
        return p;
    };
    float* xT      = (float*)alloc((size_t)T * H * B * 4);   // 256 MB
    float* pre     = (float*)alloc((size_t)T * H * B * 4);   // 256 MB (becomes outT)
    int2*  pair_ih = (int2*) alloc((size_t)NNZ * 8);
    int2*  pair_hh = (int2*) alloc((size_t)NNZ * 8);
    int*   rp_ih   = (int*)  alloc((size_t)(H + 1) * 4);
    int*   rp_hh   = (int*)  alloc((size_t)(H + 1) * 4);
    int*   cnt_ih  = (int*)  alloc((size_t)H * 4);
    int*   cnt_hh  = (int*)  alloc((size_t)H * 4);
    int*   cur_ih  = (int*)  alloc((size_t)H * 4);
    int*   cur_hh  = (int*)  alloc((size_t)H * 4);
    float* h0      = (float*)alloc((size_t)H * B * 4);
    float* h1      = (float*)alloc((size_t)H * B * 4);

    hipMemsetAsync(cnt_ih, 0, (size_t)H * 4, stream);
    hipMemsetAsync(cnt_hh, 0, (size_t)H * 4, stream);
    hipMemsetAsync(h0, 0, (size_t)H * B * 4, stream);

    const int tb = 256;
    const int gb = (NNZ + tb - 1) / tb;
    hist_kernel<<<gb, tb, 0, stream>>>(ih_rows, NNZ, cnt_ih);
    hist_kernel<<<gb, tb, 0, stream>>>(hh_rows, NNZ, cnt_hh);
    scan_kernel<<<2, 1024, 0, stream>>>(cnt_ih, rp_ih, cur_ih, cnt_hh, rp_hh, cur_hh);
    scatter_kernel<<<gb, tb, 0, stream>>>(ih_rows, ih_cols, ih_val, NNZ, cur_ih, pair_ih);
    scatter_kernel<<<gb, tb, 0, stream>>>(hh_rows, hh_cols, hh_val, NNZ, cur_hh, pair_hh);

    // x [B][T*H] -> xT [T*H][B]
    dim3 tblk(32, 8);
    dim3 tgrid1((T * H) / 32, B / 32);
    transpose_kernel<<<tgrid1, tblk, 0, stream>>>(x, xT, B, T * H);

    // all-timestep ih spmm + bias (4 rows per block, XCD-swizzled)
    ih_pre_kernel<<<(T * H) / 4, 256, 0, stream>>>(rp_ih, pair_ih, xT, pre, bias_ih, bias_hh);

    // sequential recurrence
    float* hbuf[2] = { h0, h1 };
    for (int t = 0; t < T; ++t) {
        step_kernel<<<H / 4, 256, 0, stream>>>(rp_hh, pair_hh,
                                               hbuf[t & 1], hbuf[(t + 1) & 1],
                                               pre + (size_t)t * H * B);
    }

    // outT [T*H][B] -> d_out [B][T*H]
    dim3 tgrid2(B / 32, (T * H) / 32);
    transpose_kernel<<<tgrid2, tblk, 0, stream>>>(pre, (float*)d_out, T * H, B);
}

// Round 4
// 4502.124 us; speedup vs baseline: 1.4274x; 1.4274x over previous
//
#include <hip/hip_runtime.h>
#include <cstdint>
#include <cstddef>
#include <cstring>

#define H 8192
#define NNZ 1000000
#define B 128
#define T 64

// ---------------- CSR build ----------------
__global__ void hist_kernel(const int* __restrict__ rows, int nnz, int* __restrict__ count) {
    int j = blockIdx.x * blockDim.x + threadIdx.x;
    if (j < nnz) atomicAdd(&count[rows[j]], 1);
}

// grid=2 blocks, 1024 threads: block 0 scans array A, block 1 scans array B.
__global__ void scan_kernel(const int* __restrict__ cnt0, int* __restrict__ rp0, int* __restrict__ cur0,
                            const int* __restrict__ cnt1, int* __restrict__ rp1, int* __restrict__ cur1) {
    const int* cnt = (blockIdx.x == 0) ? cnt0 : cnt1;
    int* rp  = (blockIdx.x == 0) ? rp0 : rp1;
    int* cur = (blockIdx.x == 0) ? cur0 : cur1;
    __shared__ int buf[1024];
    __shared__ int carry;
    int tid = threadIdx.x;
    if (tid == 0) carry = 0;
    __syncthreads();
    for (int base = 0; base < H; base += 1024) {
        int v = cnt[base + tid];
        buf[tid] = v;
        __syncthreads();
        for (int off = 1; off < 1024; off <<= 1) {
            int t = (tid >= off) ? buf[tid - off] : 0;
            __syncthreads();
            buf[tid] += t;
            __syncthreads();
        }
        int incl = buf[tid];
        int excl = incl - v;
        int c = carry;
        rp[base + tid]  = c + excl;
        cur[base + tid] = c + excl;
        __syncthreads();
        if (tid == 1023) carry = c + incl;
        __syncthreads();
    }
    if (tid == 0) rp[H] = carry;
}

// packs (col, val) into int2 in CSR order
__global__ void scatter_kernel(const int* __restrict__ rows, const int* __restrict__ cols,
                               const float* __restrict__ vals, int nnz,
                               int* __restrict__ cursor, int2* __restrict__ opair) {
    int j = blockIdx.x * blockDim.x + threadIdx.x;
    if (j < nnz) {
        int r = rows[j];
        int p = atomicAdd(&cursor[r], 1);
        opair[p] = make_int2(cols[j], __float_as_int(vals[j]));
    }
}

// ---------------- transpose src[R][C] -> dst[C][R]  (R,C multiples of 32) ----------------
__global__ void transpose_kernel(const float* __restrict__ src, float* __restrict__ dst,
                                 int R, int C) {
    __shared__ float tile[32][33];
    int c0 = blockIdx.x * 32, r0 = blockIdx.y * 32;
    int x = threadIdx.x, y = threadIdx.y;
    #pragma unroll
    for (int i = y; i < 32; i += 8) {
        tile[i][x] = src[(size_t)(r0 + i) * C + (c0 + x)];
    }
    __syncthreads();
    #pragma unroll
    for (int i = y; i < 32; i += 8) {
        dst[(size_t)(c0 + i) * R + (r0 + x)] = tile[x][i];
    }
}

// ---------------- ih precompute: pre[t,h,b] = bias + spmm(ih, xT[t]) ----------------
// 1 wave per block; r,t derived from blockIdx ONLY -> CSR stream is SGPR-uniform
// (s_load pairs, saddr gathers). XCD-swizzled in blockIdx space: XCD k owns
// t in [8k, 8k+8) so each 4MB x-slice is serviced by one XCD's L2.
__global__ void __launch_bounds__(64) ih_pre_kernel(
    const int* __restrict__ rp, const int2* __restrict__ pair,
    const float* __restrict__ xT, float* __restrict__ pre,
    const float* __restrict__ bias_ih, const float* __restrict__ bias_hh) {
    int bid = blockIdx.x;
    int xcd = bid & 7;
    int i   = bid >> 3;                 // per-XCD work index
    int t   = (xcd << 3) + (i >> 13);   // H = 8192 = 2^13
    int r   = i & (H - 1);
    int b2  = threadIdx.x;              // covers batch elements 2*b2, 2*b2+1
    const float2* __restrict__ xt2 = (const float2*)(xT + (size_t)t * H * B);
    float bias = bias_ih[r] + bias_hh[r];
    float ax = bias, ay = bias;
    int s = rp[r], e = rp[r + 1];
    int j = s;
    for (; j + 16 <= e; j += 16) {
        int2 p[16];
        #pragma unroll
        for (int u = 0; u < 16; ++u) p[u] = pair[j + u];
        float2 g[16];
        #pragma unroll
        for (int u = 0; u < 16; ++u) g[u] = xt2[(size_t)p[u].x * 64 + b2];
        #pragma unroll
        for (int u = 0; u < 16; ++u) {
            float v = __int_as_float(p[u].y);
            ax = fmaf(v, g[u].x, ax); ay = fmaf(v, g[u].y, ay);
        }
    }
    for (; j + 4 <= e; j += 4) {
        int2 p[4];
        #pragma unroll
        for (int u = 0; u < 4; ++u) p[u] = pair[j + u];
        float2 g[4];
        #pragma unroll
        for (int u = 0; u < 4; ++u) g[u] = xt2[(size_t)p[u].x * 64 + b2];
        #pragma unroll
        for (int u = 0; u < 4; ++u) {
            float v = __int_as_float(p[u].y);
            ax = fmaf(v, g[u].x, ax); ay = fmaf(v, g[u].y, ay);
        }
    }
    for (; j < e; ++j) {
        int2 pj = pair[j];
        float2 g = xt2[(size_t)pj.x * 64 + b2];
        float v = __int_as_float(pj.y);
        ax = fmaf(v, g.x, ax);
        ay = fmaf(v, g.y, ay);
    }
    float2 o; o.x = ax; o.y = ay;
    double od; __builtin_memcpy(&od, &o, 8);
    __builtin_nontemporal_store(od, (double*)(pre + ((size_t)t * H + r) * B) + b2);
}

// ---------------- one recurrence step: 1 wave per block, r = blockIdx ----------------
__global__ void __launch_bounds__(64) step_kernel(
    const int* __restrict__ rp, const int2* __restrict__ pair,
    const float* __restrict__ hprev, float* __restrict__ hnew, float* __restrict__ pre_t) {
    int r  = blockIdx.x;
    int b2 = threadIdx.x;
    const float2* __restrict__ h2 = (const float2*)hprev;
    double pd = __builtin_nontemporal_load((const double*)(pre_t + (size_t)r * B) + b2);
    float2 p; __builtin_memcpy(&p, &pd, 8);
    float ax = p.x, ay = p.y;
    int s = rp[r], e = rp[r + 1];
    int j = s;
    for (; j + 16 <= e; j += 16) {
        int2 q[16];
        #pragma unroll
        for (int u = 0; u < 16; ++u) q[u] = pair[j + u];
        float2 g[16];
        #pragma unroll
        for (int u = 0; u < 16; ++u) g[u] = h2[(size_t)q[u].x * 64 + b2];
        #pragma unroll
        for (int u = 0; u < 16; ++u) {
            float v = __int_as_float(q[u].y);
            ax = fmaf(v, g[u].x, ax); ay = fmaf(v, g[u].y, ay);
        }
    }
    for (; j + 4 <= e; j += 4) {
        int2 q[4];
        #pragma unroll
        for (int u = 0; u < 4; ++u) q[u] = pair[j + u];
        float2 g[4];
        #pragma unroll
        for (int u = 0; u < 4; ++u) g[u] = h2[(size_t)q[u].x * 64 + b2];
        #pragma unroll
        for (int u = 0; u < 4; ++u) {
            float v = __int_as_float(q[u].y);
            ax = fmaf(v, g[u].x, ax); ay = fmaf(v, g[u].y, ay);
        }
    }
    for (; j < e; ++j) {
        int2 qj = pair[j];
        float2 g = h2[(size_t)qj.x * 64 + b2];
        float v = __int_as_float(qj.y);
        ax = fmaf(v, g.x, ax);
        ay = fmaf(v, g.y, ay);
    }
    float hx = tanhf(ax), hy = tanhf(ay);
    float2 o; o.x = hx; o.y = hy;
    ((float2*)hnew)[(size_t)r * 64 + b2] = o;        // cached: gathered next step
    double od; __builtin_memcpy(&od, &o, 8);
    __builtin_nontemporal_store(od, (double*)(pre_t + (size_t)r * B) + b2);  // streaming outT
}

extern "C" void kernel_launch(void* const* d_in, const int* in_sizes, int n_in,
                              void* d_out, int out_size, void* d_ws, size_t ws_size,
                              hipStream_t stream) {
    const float* x        = (const float*)d_in[0];
    const int*   ih_idx   = (const int*)d_in[1];
    const float* ih_val   = (const float*)d_in[2];
    const int*   hh_idx   = (const int*)d_in[3];
    const float* hh_val   = (const float*)d_in[4];
    const float* bias_ih  = (const float*)d_in[5];
    const float* bias_hh  = (const float*)d_in[6];
    const int* ih_rows = ih_idx;
    const int* ih_cols = ih_idx + NNZ;
    const int* hh_rows = hh_idx;
    const int* hh_cols = hh_idx + NNZ;

    char* ws = (char*)d_ws;
    size_t off = 0;
    auto alloc = [&](size_t bytes) -> void* {
        void* p = ws + off;
        off += (bytes + 255) & ~(size_t)255;
        return p;
    };
    float* xT      = (float*)alloc((size_t)T * H * B * 4);   // 256 MB
    float* pre     = (float*)alloc((size_t)T * H * B * 4);   // 256 MB (becomes outT)
    int2*  pair_ih = (int2*) alloc((size_t)NNZ * 8);
    int2*  pair_hh = (int2*) alloc((size_t)NNZ * 8);
    int*   rp_ih   = (int*)  alloc((size_t)(H + 1) * 4);
    int*   rp_hh   = (int*)  alloc((size_t)(H + 1) * 4);
    int*   cnt_ih  = (int*)  alloc((size_t)H * 4);
    int*   cnt_hh  = (int*)  alloc((size_t)H * 4);
    int*   cur_ih  = (int*)  alloc((size_t)H * 4);
    int*   cur_hh  = (int*)  alloc((size_t)H * 4);
    float* h0      = (float*)alloc((size_t)H * B * 4);
    float* h1      = (float*)alloc((size_t)H * B * 4);

    hipMemsetAsync(cnt_ih, 0, (size_t)H * 4, stream);
    hipMemsetAsync(cnt_hh, 0, (size_t)H * 4, stream);
    hipMemsetAsync(h0, 0, (size_t)H * B * 4, stream);

    const int tb = 256;
    const int gb = (NNZ + tb - 1) / tb;
    hist_kernel<<<gb, tb, 0, stream>>>(ih_rows, NNZ, cnt_ih);
    hist_kernel<<<gb, tb, 0, stream>>>(hh_rows, NNZ, cnt_hh);
    scan_kernel<<<2, 1024, 0, stream>>>(cnt_ih, rp_ih, cur_ih, cnt_hh, rp_hh, cur_hh);
    scatter_kernel<<<gb, tb, 0, stream>>>(ih_rows, ih_cols, ih_val, NNZ, cur_ih, pair_ih);
    scatter_kernel<<<gb, tb, 0, stream>>>(hh_rows, hh_cols, hh_val, NNZ, cur_hh, pair_hh);

    // x [B][T*H] -> xT [T*H][B]
    dim3 tblk(32, 8);
    dim3 tgrid1((T * H) / 32, B / 32);
    transpose_kernel<<<tgrid1, tblk, 0, stream>>>(x, xT, B, T * H);

    // all-timestep ih spmm + bias (1 wave per row, XCD-swizzled in blockIdx space)
    ih_pre_kernel<<<T * H, 64, 0, stream>>>(rp_ih, pair_ih, xT, pre, bias_ih, bias_hh);

    // sequential recurrence
    float* hbuf[2] = { h0, h1 };
    for (int t = 0; t < T; ++t) {
        step_kernel<<<H, 64, 0, stream>>>(rp_hh, pair_hh,
                                          hbuf[t & 1], hbuf[(t + 1) & 1],
                                          pre + (size_t)t * H * B);
    }

    // outT [T*H][B] -> d_out [B][T*H]
    dim3 tgrid2(B / 32, (T * H) / 32);
    transpose_kernel<<<tgrid2, tblk, 0, stream>>>(pre, (float*)d_out, T * H, B);
}

// Round 5
// 2854.383 us; speedup vs baseline: 2.2514x; 1.5773x over previous
//
#include <hip/hip_runtime.h>
#include <cstdint>
#include <cstddef>
#include <cstring>

#define H 8192
#define NNZ 1000000
#define B 128
#define T 64

typedef unsigned int u32;
typedef float f32x4 __attribute__((ext_vector_type(4)));

__device__ inline float bf_lo(u32 w) { return __uint_as_float(w << 16); }
__device__ inline float bf_hi(u32 w) { return __uint_as_float(w & 0xffff0000u); }
__device__ inline unsigned short f2bf(float f) {        // RNE float->bf16
    u32 v = __float_as_uint(f);
    v += 0x7fffu + ((v >> 16) & 1u);
    return (unsigned short)(v >> 16);
}
__device__ inline u32 pack_bf16(float a, float b) {
    return (u32)f2bf(a) | ((u32)f2bf(b) << 16);
}
__device__ inline float fast_tanh(float x) {
    float e = __expf(2.0f * x);
    return 1.0f - 2.0f / (e + 1.0f);
}

// ---------------- CSR build ----------------
__global__ void hist_kernel(const int* __restrict__ rows, int nnz, int* __restrict__ count) {
    int j = blockIdx.x * blockDim.x + threadIdx.x;
    if (j < nnz) atomicAdd(&count[rows[j]], 1);
}

__global__ void scan_kernel(const int* __restrict__ cnt0, int* __restrict__ rp0, int* __restrict__ cur0,
                            const int* __restrict__ cnt1, int* __restrict__ rp1, int* __restrict__ cur1) {
    const int* cnt = (blockIdx.x == 0) ? cnt0 : cnt1;
    int* rp  = (blockIdx.x == 0) ? rp0 : rp1;
    int* cur = (blockIdx.x == 0) ? cur0 : cur1;
    __shared__ int buf[1024];
    __shared__ int carry;
    int tid = threadIdx.x;
    if (tid == 0) carry = 0;
    __syncthreads();
    for (int base = 0; base < H; base += 1024) {
        int v = cnt[base + tid];
        buf[tid] = v;
        __syncthreads();
        for (int off = 1; off < 1024; off <<= 1) {
            int t = (tid >= off) ? buf[tid - off] : 0;
            __syncthreads();
            buf[tid] += t;
            __syncthreads();
        }
        int incl = buf[tid];
        int excl = incl - v;
        int c = carry;
        rp[base + tid]  = c + excl;
        cur[base + tid] = c + excl;
        __syncthreads();
        if (tid == 1023) carry = c + incl;
        __syncthreads();
    }
    if (tid == 0) rp[H] = carry;
}

__global__ void scatter_kernel(const int* __restrict__ rows, const int* __restrict__ cols,
                               const float* __restrict__ vals, int nnz,
                               int* __restrict__ cursor, int2* __restrict__ opair) {
    int j = blockIdx.x * blockDim.x + threadIdx.x;
    if (j < nnz) {
        int r = rows[j];
        int p = atomicAdd(&cursor[r], 1);
        opair[p] = make_int2(cols[j], __float_as_int(vals[j]));
    }
}

// ---------------- fp32 transpose src[R][C] -> dst[C][R] ----------------
__global__ void transpose_kernel(const float* __restrict__ src, float* __restrict__ dst,
                                 int R, int C) {
    __shared__ float tile[32][33];
    int c0 = blockIdx.x * 32, r0 = blockIdx.y * 32;
    int x = threadIdx.x, y = threadIdx.y;
    #pragma unroll
    for (int i = y; i < 32; i += 8) {
        tile[i][x] = src[(size_t)(r0 + i) * C + (c0 + x)];
    }
    __syncthreads();
    #pragma unroll
    for (int i = y; i < 32; i += 8) {
        dst[(size_t)(c0 + i) * R + (r0 + x)] = tile[x][i];
    }
}

// ---------------- transpose + bf16-pack: x [B][T*H] fp32 -> xTb [T*H][64] u32 (bf16 pairs) ----------------
__global__ void transpose_bf16_kernel(const float* __restrict__ src, u32* __restrict__ dst) {
    __shared__ float tile[32][33];
    int c0 = blockIdx.x * 32;    // T*H dim
    int r0 = blockIdx.y * 32;    // B dim
    int x = threadIdx.x, y = threadIdx.y;
    #pragma unroll
    for (int i = y; i < 32; i += 8) {
        tile[i][x] = src[(size_t)(r0 + i) * (T * H) + (c0 + x)];
    }
    __syncthreads();
    int tid = y * 32 + x;        // 256 threads, 512 words to write
    #pragma unroll
    for (int idx = tid; idx < 32 * 16; idx += 256) {
        int row = idx >> 4, w = idx & 15;
        u32 word = pack_bf16(tile[2 * w][row], tile[2 * w + 1][row]);
        dst[(size_t)(c0 + row) * 64 + (r0 >> 1) + w] = word;
    }
}

// ---------------- ih precompute: pre[t,h,:] = bias + spmm(ih, x_t) ----------------
// 1 wave/row, blockIdx-only row derivation (scalar CSR stream), XCD swizzle (XCD k owns
// t in [8k,8k+8)). Gathers: bf16, 2 columns per instruction (lanes 0-31: even nnz col,
// lanes 32-63: odd nnz col), float4 accumulators, shfl_xor(32) combine.
__global__ void __launch_bounds__(64) ih_pre_kernel(
    const int* __restrict__ rp, const int2* __restrict__ pair,
    const u32* __restrict__ xTb, float* __restrict__ pre,
    const float* __restrict__ bias_ih, const float* __restrict__ bias_hh) {
    int bid = blockIdx.x;
    int xcd = bid & 7;
    int i0  = bid >> 3;
    int t   = (xcd << 3) + (i0 >> 13);
    int r   = i0 & (H - 1);
    int lane = threadIdx.x;
    bool hi = lane >= 32;
    int i = lane & 31;
    const uint2* __restrict__ xt = (const uint2*)(xTb + (size_t)t * H * 64);
    f32x4 acc = {0.f, 0.f, 0.f, 0.f};
    int s = rp[r], e = rp[r + 1];
    int j = s;
    for (; j + 16 <= e; j += 16) {
        int2 q[16];
        #pragma unroll
        for (int u = 0; u < 16; ++u) q[u] = pair[j + u];
        uint2 g[8];
        #pragma unroll
        for (int u = 0; u < 8; ++u) {
            int c = hi ? q[2 * u + 1].x : q[2 * u].x;
            g[u] = xt[(size_t)c * 32 + i];
        }
        #pragma unroll
        for (int u = 0; u < 8; ++u) {
            float v = __int_as_float(hi ? q[2 * u + 1].y : q[2 * u].y);
            acc.x = fmaf(v, bf_lo(g[u].x), acc.x);
            acc.y = fmaf(v, bf_hi(g[u].x), acc.y);
            acc.z = fmaf(v, bf_lo(g[u].y), acc.z);
            acc.w = fmaf(v, bf_hi(g[u].y), acc.w);
        }
    }
    for (; j + 2 <= e; j += 2) {
        int2 q0 = pair[j], q1 = pair[j + 1];
        int c = hi ? q1.x : q0.x;
        uint2 g = xt[(size_t)c * 32 + i];
        float v = __int_as_float(hi ? q1.y : q0.y);
        acc.x = fmaf(v, bf_lo(g.x), acc.x);
        acc.y = fmaf(v, bf_hi(g.x), acc.y);
        acc.z = fmaf(v, bf_lo(g.y), acc.z);
        acc.w = fmaf(v, bf_hi(g.y), acc.w);
    }
    if (j < e) {
        int2 q0 = pair[j];
        uint2 g = xt[(size_t)q0.x * 32 + i];
        float v = hi ? 0.0f : __int_as_float(q0.y);
        acc.x = fmaf(v, bf_lo(g.x), acc.x);
        acc.y = fmaf(v, bf_hi(g.x), acc.y);
        acc.z = fmaf(v, bf_lo(g.y), acc.z);
        acc.w = fmaf(v, bf_hi(g.y), acc.w);
    }
    f32x4 tot;
    tot.x = acc.x + __shfl_xor(acc.x, 32, 64);
    tot.y = acc.y + __shfl_xor(acc.y, 32, 64);
    tot.z = acc.z + __shfl_xor(acc.z, 32, 64);
    tot.w = acc.w + __shfl_xor(acc.w, 32, 64);
    if (lane < 32) {
        float bias = bias_ih[r] + bias_hh[r];
        tot.x += bias; tot.y += bias; tot.z += bias; tot.w += bias;
        __builtin_nontemporal_store(tot, (f32x4*)(pre + ((size_t)t * H + r) * B) + i);
    }
}

// ---------------- one recurrence step ----------------
// h stored bf16-packed [H][64] u32 for the gathers; fp32 tanh result goes to pre_t (outT).
__global__ void __launch_bounds__(64) step_kernel(
    const int* __restrict__ rp, const int2* __restrict__ pair,
    const u32* __restrict__ hprev, u32* __restrict__ hnew, float* __restrict__ pre_t) {
    int r = blockIdx.x;
    int lane = threadIdx.x;
    bool hi = lane >= 32;
    int i = lane & 31;
    const uint2* __restrict__ hp = (const uint2*)hprev;
    f32x4 acc = {0.f, 0.f, 0.f, 0.f};
    int s = rp[r], e = rp[r + 1];
    int j = s;
    for (; j + 16 <= e; j += 16) {
        int2 q[16];
        #pragma unroll
        for (int u = 0; u < 16; ++u) q[u] = pair[j + u];
        uint2 g[8];
        #pragma unroll
        for (int u = 0; u < 8; ++u) {
            int c = hi ? q[2 * u + 1].x : q[2 * u].x;
            g[u] = hp[(size_t)c * 32 + i];
        }
        #pragma unroll
        for (int u = 0; u < 8; ++u) {
            float v = __int_as_float(hi ? q[2 * u + 1].y : q[2 * u].y);
            acc.x = fmaf(v, bf_lo(g[u].x), acc.x);
            acc.y = fmaf(v, bf_hi(g[u].x), acc.y);
            acc.z = fmaf(v, bf_lo(g[u].y), acc.z);
            acc.w = fmaf(v, bf_hi(g[u].y), acc.w);
        }
    }
    for (; j + 2 <= e; j += 2) {
        int2 q0 = pair[j], q1 = pair[j + 1];
        int c = hi ? q1.x : q0.x;
        uint2 g = hp[(size_t)c * 32 + i];
        float v = __int_as_float(hi ? q1.y : q0.y);
        acc.x = fmaf(v, bf_lo(g.x), acc.x);
        acc.y = fmaf(v, bf_hi(g.x), acc.y);
        acc.z = fmaf(v, bf_lo(g.y), acc.z);
        acc.w = fmaf(v, bf_hi(g.y), acc.w);
    }
    if (j < e) {
        int2 q0 = pair[j];
        uint2 g = hp[(size_t)q0.x * 32 + i];
        float v = hi ? 0.0f : __int_as_float(q0.y);
        acc.x = fmaf(v, bf_lo(g.x), acc.x);
        acc.y = fmaf(v, bf_hi(g.x), acc.y);
        acc.z = fmaf(v, bf_lo(g.y), acc.z);
        acc.w = fmaf(v, bf_hi(g.y), acc.w);
    }
    f32x4 tot;
    tot.x = acc.x + __shfl_xor(acc.x, 32, 64);
    tot.y = acc.y + __shfl_xor(acc.y, 32, 64);
    tot.z = acc.z + __shfl_xor(acc.z, 32, 64);
    tot.w = acc.w + __shfl_xor(acc.w, 32, 64);
    if (lane < 32) {
        f32x4 p = __builtin_nontemporal_load((const f32x4*)(pre_t + (size_t)r * B) + i);
        float h0 = fast_tanh(tot.x + p.x);
        float h1 = fast_tanh(tot.y + p.y);
        float h2 = fast_tanh(tot.z + p.z);
        float h3 = fast_tanh(tot.w + p.w);
        f32x4 o = {h0, h1, h2, h3};
        __builtin_nontemporal_store(o, (f32x4*)(pre_t + (size_t)r * B) + i);  // outT (fp32)
        uint2 hw;
        hw.x = pack_bf16(h0, h1);
        hw.y = pack_bf16(h2, h3);
        ((uint2*)hnew)[(size_t)r * 32 + i] = hw;                              // next-step operand (bf16)
    }
}

extern "C" void kernel_launch(void* const* d_in, const int* in_sizes, int n_in,
                              void* d_out, int out_size, void* d_ws, size_t ws_size,
                              hipStream_t stream) {
    const float* x        = (const float*)d_in[0];
    const int*   ih_idx   = (const int*)d_in[1];
    const float* ih_val   = (const float*)d_in[2];
    const int*   hh_idx   = (const int*)d_in[3];
    const float* hh_val   = (const float*)d_in[4];
    const float* bias_ih  = (const float*)d_in[5];
    const float* bias_hh  = (const float*)d_in[6];
    const int* ih_rows = ih_idx;
    const int* ih_cols = ih_idx + NNZ;
    const int* hh_rows = hh_idx;
    const int* hh_cols = hh_idx + NNZ;

    char* ws = (char*)d_ws;
    size_t off = 0;
    auto alloc = [&](size_t bytes) -> void* {
        void* p = ws + off;
        off += (bytes + 255) & ~(size_t)255;
        return p;
    };
    u32*   xTb     = (u32*)  alloc((size_t)T * H * 64 * 4);  // 128 MB bf16-packed
    float* pre     = (float*)alloc((size_t)T * H * B * 4);   // 256 MB (becomes outT)
    int2*  pair_ih = (int2*) alloc((size_t)NNZ * 8);
    int2*  pair_hh = (int2*) alloc((size_t)NNZ * 8);
    int*   rp_ih   = (int*)  alloc((size_t)(H + 1) * 4);
    int*   rp_hh   = (int*)  alloc((size_t)(H + 1) * 4);
    int*   cnt_ih  = (int*)  alloc((size_t)H * 4);
    int*   cnt_hh  = (int*)  alloc((size_t)H * 4);
    int*   cur_ih  = (int*)  alloc((size_t)H * 4);
    int*   cur_hh  = (int*)  alloc((size_t)H * 4);
    u32*   h0      = (u32*)  alloc((size_t)H * 64 * 4);      // bf16-packed h
    u32*   h1      = (u32*)  alloc((size_t)H * 64 * 4);

    hipMemsetAsync(cnt_ih, 0, (size_t)H * 4, stream);
    hipMemsetAsync(cnt_hh, 0, (size_t)H * 4, stream);
    hipMemsetAsync(h0, 0, (size_t)H * 64 * 4, stream);

    const int tb = 256;
    const int gb = (NNZ + tb - 1) / tb;
    hist_kernel<<<gb, tb, 0, stream>>>(ih_rows, NNZ, cnt_ih);
    hist_kernel<<<gb, tb, 0, stream>>>(hh_rows, NNZ, cnt_hh);
    scan_kernel<<<2, 1024, 0, stream>>>(cnt_ih, rp_ih, cur_ih, cnt_hh, rp_hh, cur_hh);
    scatter_kernel<<<gb, tb, 0, stream>>>(ih_rows, ih_cols, ih_val, NNZ, cur_ih, pair_ih);
    scatter_kernel<<<gb, tb, 0, stream>>>(hh_rows, hh_cols, hh_val, NNZ, cur_hh, pair_hh);

    // x [B][T*H] fp32 -> xTb [T*H][64] bf16-pairs
    dim3 tblk(32, 8);
    dim3 tgrid1((T * H) / 32, B / 32);
    transpose_bf16_kernel<<<tgrid1, tblk, 0, stream>>>(x, xTb);

    // all-timestep ih spmm + bias
    ih_pre_kernel<<<T * H, 64, 0, stream>>>(rp_ih, pair_ih, xTb, pre, bias_ih, bias_hh);

    // sequential recurrence
    u32* hbuf[2] = { h0, h1 };
    for (int t = 0; t < T; ++t) {
        step_kernel<<<H, 64, 0, stream>>>(rp_hh, pair_hh,
                                          hbuf[t & 1], hbuf[(t + 1) & 1],
                                          pre + (size_t)t * H * B);
    }

    // outT [T*H][B] -> d_out [B][T*H]
    dim3 tgrid2(B / 32, (T * H) / 32);
    transpose_kernel<<<tgrid2, tblk, 0, stream>>>(pre, (float*)d_out, T * H, B);
}